// Round 2
// baseline (157.057 us; speedup 1.0000x reference)
//
#include <hip/hip_runtime.h>
#include <hip/hip_fp16.h>

// MinGRU single-pass fused pipeline, round 9 = round 8 + software-pipelined
// K loop (T14 async-stage split). X loads for tile k+1 are issued into
// registers BEFORE the MFMA phase of tile k, so the compiler's mandatory
// vmcnt(0) drain at the post-MFMA barrier lands long after issue and the
// HBM latency hides under ds_read+MFMA (and the other 3 blocks on the CU).
// After that barrier only cvt+ds_write (lgkm) and the W global_load_lds
// (L2-hit, W is 512 KB hot) remain exposed. sched_barrier(0) pins the
// prefetch issues above the MFMA cluster; s_setprio(1) wraps the MFMA
// cluster (T5 - blocks on a CU are phase-diverse here).
// Everything else (swizzle, epilogue, batched lookback, nontemporal out)
// is byte-identical to round 8.
// Swizzle scheme (unchanged): row = 8 x 16B blocks; global block b of row r
// lives at LDS slot b ^ (r & 7).

namespace {
constexpr int kB  = 8;
constexpr int kT  = 4096;
constexpr int kD  = 256;
constexpr int kH  = 256;
constexpr int kBT = kB * kT;

constexpr int TM  = 128;          // time rows per block
constexpr int TH  = 64;           // h cols per block (dual-W => 128 eff. N)
constexpr int BK  = 64;           // GEMM k tile
constexpr int kNT = kT / TM;      // 32 time-tiles per chain
constexpr int kNChain = kB * (kH / TH);   // 32 chains
constexpr int EPS = 66;           // epilogue LDS row stride (half)
} // namespace

typedef short s16x8 __attribute__((ext_vector_type(8)));
typedef short s16x4 __attribute__((ext_vector_type(4)));
typedef float f32x4 __attribute__((ext_vector_type(4)));

__device__ __forceinline__ short f2bf(float f) {
    union { float f; unsigned int u; } v; v.f = f;
    unsigned int r = v.u + 0x7fffu + ((v.u >> 16) & 1u);   // RNE
    return (short)(r >> 16);
}

// packed RNE f32x2 -> bf16x2 (low word = lo operand); same rounding as f2bf
__device__ __forceinline__ unsigned int cvt_pk_bf16(float lo, float hi) {
    unsigned int r;
    asm("v_cvt_pk_bf16_f32 %0, %1, %2" : "=v"(r) : "v"(lo), "v"(hi));
    return r;
}

__device__ __forceinline__ void load_lds16(const void* g, void* l) {
    __builtin_amdgcn_global_load_lds(
        (const __attribute__((address_space(1))) void*)g,
        (__attribute__((address_space(3))) void*)l, 16, 0, 0);
}

// ---------------------------------------------------------------------------
// Kernel 1 (tiny): fp32 -> bf16 for Wz, Wh; zero the 512 KB aggregate mailbox.
// ---------------------------------------------------------------------------
__global__ __launch_bounds__(256)
void prep(const float* __restrict__ Wz,
          const float* __restrict__ Wh,
          unsigned short* __restrict__ wzb,
          unsigned short* __restrict__ whb,
          float4* __restrict__ aggz)
{
    constexpr int W4 = kH * kD / 4;           // 16,384 each
    const int i = blockIdx.x * 256 + threadIdx.x;

    if (i >= 2 * W4) {                        // zero mailbox (32768 float4)
        float4 z; z.x = 0.f; z.y = 0.f; z.z = 0.f; z.w = 0.f;
        aggz[i - 2 * W4] = z;
        return;
    }
    const float* src; unsigned short* dst; int j;
    if (i < W4) { src = Wz; dst = wzb; j = i; }
    else        { src = Wh; dst = whb; j = i - W4; }
    const float4 v = ((const float4*)src)[j];
    s16x4 p;
    p[0] = f2bf(v.x); p[1] = f2bf(v.y); p[2] = f2bf(v.z); p[3] = f2bf(v.w);
    ((s16x4*)dst)[j] = p;
}

// ---------------------------------------------------------------------------
// Kernel 2: fused convert + pipelined GEMM + sigmoid + block aggregate +
// lookback + apply + out. Grid: dim3(kNChain=32, kNT=32). 4 waves/block,
// 4 blocks/CU (all 1024 resident).
// ---------------------------------------------------------------------------
__global__ __launch_bounds__(256, 4)
void gemm_scan_fused(const float* __restrict__ x,
                     const unsigned short* __restrict__ wzb,
                     const unsigned short* __restrict__ whb,
                     const float* __restrict__ bz,
                     const float* __restrict__ bh,
                     const float* __restrict__ h0,
                     unsigned long long* __restrict__ agg,  // [32 chains][32 t][64 h]
                     float* __restrict__ out)
{
    // LDS: staging Xs[128][64] | Wzs[64][64] | Whs[64][64] ushort (32KB,
    // XOR-swizzled 16B blocks), overlaid after the K loop by a_lds/b_lds
    // [128][66] half; + sub_lds[4][64] float2 @33792 ; + hs_lds[64] @35840.
    __shared__ __align__(16) unsigned char smem[36096];
    unsigned short* Xs  = (unsigned short*)smem;
    unsigned short* Wzs = Xs  + 128 * 64;
    unsigned short* Whs = Wzs + 64 * 64;
    __half* a_lds   = (__half*)smem;                 // [128][EPS]
    __half* b_lds   = a_lds + 128 * EPS;
    float2* sub_lds = (float2*)(smem + 33792);       // [4][64]
    float*  hs_lds  = (float*)(smem + 35840);        // [64]

    const int tid  = threadIdx.x;
    const int lane = tid & 63;
    const int wv   = tid >> 6;
    const int ln15 = lane & 15;
    const int quad = lane >> 4;
    const int wr0  = (wv & 1) * 64;
    const int wc0  = (wv >> 1) * 32;

    const int chain = blockIdx.x;            // 0..31
    const int t     = blockIdx.y;            // 0..31 (time-tile in chain)
    const int b     = chain >> 2;
    const int col0  = (chain & 3) * TH;
    const int row0  = b * kT + t * TM;       // global BT row of tile top

    // W staging geometry (DMA path): segments of 8 rows x 128B; lane covers
    // row seg*8 + (lane>>3), LDS 16B slot (lane&7); fetched global block =
    // slot ^ srow since (abs row)&7 == srow.
    const int srow = lane >> 3;              // 0..7
    const int swslot = (lane & 7) ^ srow;    // swizzled global 16B block

    // X prefetch state: thread covers 4 of the 1024 16B-bf16 blocks of the
    // tile: bi = j*256+tid, r = bi>>3 (0..127), blk = bi&7. Held fp32 in
    // regs (8 x float4 = 32 VGPR) across the MFMA phase, converted at write.
    const int xr   = (tid >> 3) & 127;       // row covered at j=0 (r for bi=tid)
    float4 xv0[4], xv1[4];

    f32x4 accZ[4][2] = {};
    f32x4 accU[4][2] = {};

    // ---- prologue: stage tile k0=0 (X regs + W DMA), write, sync
    #pragma unroll
    for (int j = 0; j < 4; ++j) {
        const int bi  = j * 256 + tid;
        const int r   = bi >> 3;
        const int blk = bi & 7;
        const float* src = x + (size_t)(row0 + r) * kD + blk * 8;
        xv0[j] = *(const float4*)src;
        xv1[j] = *(const float4*)(src + 4);
    }
    #pragma unroll
    for (int s = 0; s < 2; ++s) {
        const int seg = wv * 2 + s;                  // 0..7
        const int m = seg * 8 + srow;                // 0..63
        load_lds16(wzb + (size_t)(col0 + m) * kD + swslot * 8,
                   Wzs + seg * 512);
        load_lds16(whb + (size_t)(col0 + m) * kD + swslot * 8,
                   Whs + seg * 512);
    }
    #pragma unroll
    for (int j = 0; j < 4; ++j) {
        const int bi  = j * 256 + tid;
        const int r   = bi >> 3;
        const int blk = bi & 7;
        union { unsigned int u[4]; s16x8 v; } pk;
        pk.u[0] = cvt_pk_bf16(xv0[j].x, xv0[j].y);
        pk.u[1] = cvt_pk_bf16(xv0[j].z, xv0[j].w);
        pk.u[2] = cvt_pk_bf16(xv1[j].x, xv1[j].y);
        pk.u[3] = cvt_pk_bf16(xv1[j].z, xv1[j].w);
        *(s16x8*)&Xs[r * 64 + ((blk ^ (r & 7)) << 3)] = pk.v;
    }
    __syncthreads();   // drains X ds_writes (lgkm) + W DMA (vmcnt)

    // ---- pipelined K loop
    #pragma unroll
    for (int k = 0; k < 4; ++k) {
        const int k0n = (k + 1) * BK;
        if (k < 3) {
            // issue next tile's X loads NOW; they drain at the post-MFMA
            // barrier, ~the whole MFMA phase after issue.
            #pragma unroll
            for (int j = 0; j < 4; ++j) {
                const int bi  = j * 256 + tid;
                const int r   = bi >> 3;
                const int blk = bi & 7;
                const float* src = x + (size_t)(row0 + r) * kD + k0n + blk * 8;
                xv0[j] = *(const float4*)src;
                xv1[j] = *(const float4*)(src + 4);
            }
        }
        __builtin_amdgcn_sched_barrier(0);   // keep loads above the MFMA phase

        #pragma unroll
        for (int kk = 0; kk < BK; kk += 32) {
            const int bblk = (kk >> 3) + quad;           // global 16B block 0..7
            s16x8 af[4], bzf[2], buf[2];
            #pragma unroll
            for (int mt = 0; mt < 4; ++mt) {
                const int r = wr0 + mt * 16 + ln15;
                af[mt] = *(const s16x8*)&Xs[r * 64 + ((bblk ^ (r & 7)) << 3)];
            }
            #pragma unroll
            for (int nt = 0; nt < 2; ++nt) {
                const int rw = wc0 + nt * 16 + ln15;
                const int so = (bblk ^ (rw & 7)) << 3;
                bzf[nt] = *(const s16x8*)&Wzs[rw * 64 + so];
                buf[nt] = *(const s16x8*)&Whs[rw * 64 + so];
            }
            __builtin_amdgcn_s_setprio(1);
            #pragma unroll
            for (int mt = 0; mt < 4; ++mt) {
                #pragma unroll
                for (int nt = 0; nt < 2; ++nt) {
                    accZ[mt][nt] = __builtin_amdgcn_mfma_f32_16x16x32_bf16(
                        af[mt], bzf[nt], accZ[mt][nt], 0, 0, 0);
                    accU[mt][nt] = __builtin_amdgcn_mfma_f32_16x16x32_bf16(
                        af[mt], buf[nt], accU[mt][nt], 0, 0, 0);
                }
            }
            __builtin_amdgcn_s_setprio(0);
        }
        __syncthreads();   // all waves done READING Xs/Wzs/Whs (drains X loads)

        if (k < 3) {
            // stage next tile: W via DMA (L2-hit), X from regs (already here).
            #pragma unroll
            for (int s = 0; s < 2; ++s) {
                const int seg = wv * 2 + s;
                const int m = seg * 8 + srow;
                load_lds16(wzb + (size_t)(col0 + m) * kD + k0n + swslot * 8,
                           Wzs + seg * 512);
                load_lds16(whb + (size_t)(col0 + m) * kD + k0n + swslot * 8,
                           Whs + seg * 512);
            }
            #pragma unroll
            for (int j = 0; j < 4; ++j) {
                const int bi  = j * 256 + tid;
                const int r   = bi >> 3;
                const int blk = bi & 7;
                union { unsigned int u[4]; s16x8 v; } pk;
                pk.u[0] = cvt_pk_bf16(xv0[j].x, xv0[j].y);
                pk.u[1] = cvt_pk_bf16(xv0[j].z, xv0[j].w);
                pk.u[2] = cvt_pk_bf16(xv1[j].x, xv1[j].y);
                pk.u[3] = cvt_pk_bf16(xv1[j].z, xv1[j].w);
                *(s16x8*)&Xs[r * 64 + ((blk ^ (r & 7)) << 3)] = pk.v;
            }
            __syncthreads();   // drain W DMA + X ds_writes
        }
    }
    (void)xr;

    // ---- epilogue: sigmoid; a/bb -> LDS fp16 (C/D: col=ln15, row=quad*4+r)
    #pragma unroll
    for (int nt = 0; nt < 2; ++nt) {
        const int col = col0 + wc0 + nt * 16 + ln15;
        const int lc  = wc0 + nt * 16 + ln15;
        const float bzv = bz[col];
        const float bhv = bh[col];
        #pragma unroll
        for (int mt = 0; mt < 4; ++mt) {
            const int rb = wr0 + mt * 16 + quad * 4;
            #pragma unroll
            for (int r = 0; r < 4; ++r) {
                const float z = accZ[mt][nt][r] + bzv;
                const float g = 1.0f / (1.0f + __expf(-z));
                const float u = accU[mt][nt][r] + bhv;
                a_lds[(rb + r) * EPS + lc] = __float2half_rn(1.0f - g);
                b_lds[(rb + r) * EPS + lc] = __float2half_rn(g * u);
            }
        }
    }
    __syncthreads();

    // ---- sub-chunk (32-row) affine summaries: thread (s,h)
    const int s = tid >> 6;
    const int h = tid & 63;
    {
        float A = 1.0f, Bv = 0.0f;
        #pragma unroll 8
        for (int r = s * 32; r < s * 32 + 32; ++r) {
            const float a  = __half2float(a_lds[r * EPS + h]);
            const float bb = __half2float(b_lds[r * EPS + h]);
            Bv = fmaf(a, Bv, bb);
            A *= a;
        }
        float2 o; o.x = A; o.y = Bv;
        sub_lds[s * 64 + h] = o;
    }
    __syncthreads();

    // ---- publish block aggregate + batched lookback (one lane per h)
    if (tid < 64) {
        float A = 1.0f, Bv = 0.0f;
        #pragma unroll
        for (int s2 = 0; s2 < 4; ++s2) {
            const float2 g = sub_lds[s2 * 64 + tid];
            Bv = fmaf(g.x, Bv, g.y);
            A *= g.x;
        }
        union { float2 f; unsigned long long u; } pk;
        pk.f.x = A; pk.f.y = Bv;
        pk.u |= 1ull;                         // never 0 => unambiguous ready flag
        __hip_atomic_store(&agg[(size_t)(chain * kNT + t) * 64 + tid], pk.u,
                           __ATOMIC_RELAXED, __HIP_MEMORY_SCOPE_AGENT);

        // lookback over predecessors 0..t-1, 8 at a time (independent loads,
        // one L2/L3 latency per batch; fold strictly in order).
        float hs = h0[(size_t)b * kH + col0 + tid];
        for (int j0 = 0; j0 < t; j0 += 8) {
            const int nb = (t - j0 < 8) ? (t - j0) : 8;
            unsigned long long u[8];
            #pragma unroll
            for (int q = 0; q < 8; ++q)
                if (q < nb)
                    u[q] = __hip_atomic_load(
                        &agg[(size_t)(chain * kNT + j0 + q) * 64 + tid],
                        __ATOMIC_RELAXED, __HIP_MEMORY_SCOPE_AGENT);
            #pragma unroll
            for (int q = 0; q < 8; ++q) {
                if (q < nb) {
                    while (u[q] == 0ull)
                        u[q] = __hip_atomic_load(
                            &agg[(size_t)(chain * kNT + j0 + q) * 64 + tid],
                            __ATOMIC_RELAXED, __HIP_MEMORY_SCOPE_AGENT);
                    union { unsigned long long u; float2 f; } qk; qk.u = u[q];
                    hs = fmaf(qk.f.x, hs, qk.f.y);
                }
            }
        }
        hs_lds[tid] = hs;
    }
    __syncthreads();

    // ---- apply recurrence: thread (s,h) does its 32 rows, writes out
    {
        float hv = hs_lds[h];
        #pragma unroll
        for (int s2 = 0; s2 < s; ++s2) {
            const float2 g = sub_lds[s2 * 64 + h];
            hv = fmaf(g.x, hv, g.y);
        }
        #pragma unroll 8
        for (int r = 0; r < 32; ++r) {
            const int lr = s * 32 + r;
            const float a  = __half2float(a_lds[lr * EPS + h]);
            const float bb = __half2float(b_lds[lr * EPS + h]);
            hv = fmaf(a, hv, bb);
            __builtin_nontemporal_store(hv, &out[(size_t)(row0 + lr) * kH + col0 + h]);
        }
    }
}

extern "C" void kernel_launch(void* const* d_in, const int* in_sizes, int n_in,
                              void* d_out, int out_size, void* d_ws, size_t ws_size,
                              hipStream_t stream)
{
    const float* x  = (const float*)d_in[0];
    const float* h0 = (const float*)d_in[1];
    const float* Wz = (const float*)d_in[2];
    const float* bz = (const float*)d_in[3];
    const float* Wh = (const float*)d_in[4];
    const float* bh = (const float*)d_in[5];
    float* out = (float*)d_out;

    // Workspace: wzb/whb 131K each | agg 512K  => ~0.8 MB.
    unsigned char* ws = (unsigned char*)d_ws;
    unsigned short* wzb = (unsigned short*)ws;   ws += (size_t)kH * kD * 2;
    unsigned short* whb = (unsigned short*)ws;   ws += (size_t)kH * kD * 2;
    unsigned long long* agg = (unsigned long long*)ws;

    constexpr int PREP_ITEMS = 2 * (kH * kD / 4)
                             + kNChain * kNT * TH * 8 / 16;   // 65,536
    prep<<<PREP_ITEMS / 256, 256, 0, stream>>>(
        Wz, Wh, wzb, whb, (float4*)agg);
    gemm_scan_fused<<<dim3(kNChain, kNT), 256, 0, stream>>>(
        x, wzb, whb, bz, bh, h0, agg, out);
}

// Round 3
// 114.165 us; speedup vs baseline: 1.3757x; 1.3757x over previous
//
#include <hip/hip_runtime.h>
#include <hip/hip_fp16.h>

// MinGRU single-pass fused pipeline, round 10 = round 8 (the 45.5us kernel)
// + XCD co-location swizzle. Round 9's reg-prefetch pipeline spilled: the
// kernel sits at exactly the (256,4) unified VGPR+AGPR cap (64+64=128), so
// the 32 prefetch VGPRs went to scratch (+50MB FETCH / +86MB WRITE => 80us).
// Reverted. This round: the 4 col-group blocks sharing an X tile (same b,t)
// were dispatched at consecutive ids -> different XCDs -> each missed to
// HBM separately (FETCH 68MB ~ 2x of x). Bijective id swizzle puts them in
// the same id%8 class -> same XCD -> one HBM fetch + 3 L2 hits per tile.
// id = (bt%8) + 8*(cg + 4*(bt>>3)); bt = b*32+t. Zero register cost, full
// residency (4 blocks/CU) preserved, body byte-identical to round 8.
// Swizzle scheme (unchanged): row = 8 x 16B blocks; global block b of row r
// lives at LDS slot b ^ (r & 7).

namespace {
constexpr int kB  = 8;
constexpr int kT  = 4096;
constexpr int kD  = 256;
constexpr int kH  = 256;
constexpr int kBT = kB * kT;

constexpr int TM  = 128;          // time rows per block
constexpr int TH  = 64;           // h cols per block (dual-W => 128 eff. N)
constexpr int BK  = 64;           // GEMM k tile
constexpr int kNT = kT / TM;      // 32 time-tiles per chain
constexpr int kNChain = kB * (kH / TH);   // 32 chains
constexpr int EPS = 66;           // epilogue LDS row stride (half)
} // namespace

typedef short s16x8 __attribute__((ext_vector_type(8)));
typedef short s16x4 __attribute__((ext_vector_type(4)));
typedef float f32x4 __attribute__((ext_vector_type(4)));

__device__ __forceinline__ short f2bf(float f) {
    union { float f; unsigned int u; } v; v.f = f;
    unsigned int r = v.u + 0x7fffu + ((v.u >> 16) & 1u);   // RNE
    return (short)(r >> 16);
}

// packed RNE f32x2 -> bf16x2 (low word = lo operand); same rounding as f2bf
__device__ __forceinline__ unsigned int cvt_pk_bf16(float lo, float hi) {
    unsigned int r;
    asm("v_cvt_pk_bf16_f32 %0, %1, %2" : "=v"(r) : "v"(lo), "v"(hi));
    return r;
}

__device__ __forceinline__ void load_lds16(const void* g, void* l) {
    __builtin_amdgcn_global_load_lds(
        (const __attribute__((address_space(1))) void*)g,
        (__attribute__((address_space(3))) void*)l, 16, 0, 0);
}

// ---------------------------------------------------------------------------
// Kernel 1 (tiny): fp32 -> bf16 for Wz, Wh; zero the 512 KB aggregate mailbox.
// ---------------------------------------------------------------------------
__global__ __launch_bounds__(256)
void prep(const float* __restrict__ Wz,
          const float* __restrict__ Wh,
          unsigned short* __restrict__ wzb,
          unsigned short* __restrict__ whb,
          float4* __restrict__ aggz)
{
    constexpr int W4 = kH * kD / 4;           // 16,384 each
    const int i = blockIdx.x * 256 + threadIdx.x;

    if (i >= 2 * W4) {                        // zero mailbox (32768 float4)
        float4 z; z.x = 0.f; z.y = 0.f; z.z = 0.f; z.w = 0.f;
        aggz[i - 2 * W4] = z;
        return;
    }
    const float* src; unsigned short* dst; int j;
    if (i < W4) { src = Wz; dst = wzb; j = i; }
    else        { src = Wh; dst = whb; j = i - W4; }
    const float4 v = ((const float4*)src)[j];
    s16x4 p;
    p[0] = f2bf(v.x); p[1] = f2bf(v.y); p[2] = f2bf(v.z); p[3] = f2bf(v.w);
    ((s16x4*)dst)[j] = p;
}

// ---------------------------------------------------------------------------
// Kernel 2: fused convert + GEMM + sigmoid + block aggregate + lookback +
// apply + out. Grid: 1024 blocks (XCD-swizzled 1-D). 4 waves/block,
// 4 blocks/CU (all 1024 resident).
// ---------------------------------------------------------------------------
__global__ __launch_bounds__(256, 4)
void gemm_scan_fused(const float* __restrict__ x,
                     const unsigned short* __restrict__ wzb,
                     const unsigned short* __restrict__ whb,
                     const float* __restrict__ bz,
                     const float* __restrict__ bh,
                     const float* __restrict__ h0,
                     unsigned long long* __restrict__ agg,  // [32 chains][32 t][64 h]
                     float* __restrict__ out)
{
    // LDS: staging Xs[128][64] | Wzs[64][64] | Whs[64][64] ushort (32KB,
    // XOR-swizzled 16B blocks), overlaid after the K loop by a_lds/b_lds
    // [128][66] half; + sub_lds[4][64] float2 @33792 ; + hs_lds[64] @35840.
    __shared__ __align__(16) unsigned char smem[36096];
    unsigned short* Xs  = (unsigned short*)smem;
    unsigned short* Wzs = Xs  + 128 * 64;
    unsigned short* Whs = Wzs + 64 * 64;
    __half* a_lds   = (__half*)smem;                 // [128][EPS]
    __half* b_lds   = a_lds + 128 * EPS;
    float2* sub_lds = (float2*)(smem + 33792);       // [4][64]
    float*  hs_lds  = (float*)(smem + 35840);        // [64]

    const int tid  = threadIdx.x;
    const int lane = tid & 63;
    const int wv   = tid >> 6;
    const int ln15 = lane & 15;
    const int quad = lane >> 4;
    const int wr0  = (wv & 1) * 64;
    const int wc0  = (wv >> 1) * 32;

    // XCD co-location decode: the 4 col-groups of one (b,t) share id%8
    // (=> same XCD, shared X tile in that XCD's L2). Bijective over 1024.
    const int id  = blockIdx.x;
    const int r8  = id & 7;
    const int q   = id >> 3;
    const int cg  = q & 3;                   // col-group 0..3
    const int bt  = (q >> 2) * 8 + r8;       // 0..255
    const int b   = bt >> 5;
    const int t   = bt & 31;                 // time-tile in chain
    const int chain = b * 4 + cg;            // 0..31
    const int col0  = cg * TH;
    const int row0  = b * kT + t * TM;       // global BT row of tile top

    // W staging geometry (DMA path): segments of 8 rows x 128B; lane covers
    // row seg*8 + (lane>>3), LDS 16B slot (lane&7); fetched global block =
    // slot ^ srow since (abs row)&7 == srow.
    const int srow = lane >> 3;              // 0..7
    const int swslot = (lane & 7) ^ srow;    // swizzled global 16B block

    f32x4 accZ[4][2] = {};
    f32x4 accU[4][2] = {};

    for (int k0 = 0; k0 < kD; k0 += BK) {
        // W: async DMA first so it flies under the X reg-staging.
        #pragma unroll
        for (int s = 0; s < 2; ++s) {
            const int seg = wv * 2 + s;                  // 0..7
            const int m = seg * 8 + srow;                // 0..63
            load_lds16(wzb + (size_t)(col0 + m) * kD + k0 + swslot * 8,
                       Wzs + seg * 512);
            load_lds16(whb + (size_t)(col0 + m) * kD + k0 + swslot * 8,
                       Whs + seg * 512);
        }
        // X: fp32 global -> bf16 regs -> swizzled LDS. Thread covers 4 of the
        // 1024 16B-bf16 blocks: bi = j*256+tid, r = bi>>3 (0..127), blk = bi&7.
        // Per instr the wave touches 8 rows x full 256B k-width: coalesced.
        #pragma unroll
        for (int j = 0; j < 4; ++j) {
            const int bi  = j * 256 + tid;
            const int r   = bi >> 3;
            const int blk = bi & 7;
            const float* src = x + (size_t)(row0 + r) * kD + k0 + blk * 8;
            const float4 v0 = *(const float4*)src;
            const float4 v1 = *(const float4*)(src + 4);
            union { unsigned int u[4]; s16x8 v; } pk;
            pk.u[0] = cvt_pk_bf16(v0.x, v0.y);
            pk.u[1] = cvt_pk_bf16(v0.z, v0.w);
            pk.u[2] = cvt_pk_bf16(v1.x, v1.y);
            pk.u[3] = cvt_pk_bf16(v1.z, v1.w);
            *(s16x8*)&Xs[r * 64 + ((blk ^ (r & 7)) << 3)] = pk.v;
        }
        __syncthreads();   // drain DMA + ds_writes

        #pragma unroll
        for (int kk = 0; kk < BK; kk += 32) {
            const int bblk = (kk >> 3) + quad;           // global 16B block 0..7
            s16x8 af[4], bzf[2], buf[2];
            #pragma unroll
            for (int mt = 0; mt < 4; ++mt) {
                const int r = wr0 + mt * 16 + ln15;
                af[mt] = *(const s16x8*)&Xs[r * 64 + ((bblk ^ (r & 7)) << 3)];
            }
            #pragma unroll
            for (int nt = 0; nt < 2; ++nt) {
                const int rw = wc0 + nt * 16 + ln15;
                const int so = (bblk ^ (rw & 7)) << 3;
                bzf[nt] = *(const s16x8*)&Wzs[rw * 64 + so];
                buf[nt] = *(const s16x8*)&Whs[rw * 64 + so];
            }
            #pragma unroll
            for (int mt = 0; mt < 4; ++mt) {
                #pragma unroll
                for (int nt = 0; nt < 2; ++nt) {
                    accZ[mt][nt] = __builtin_amdgcn_mfma_f32_16x16x32_bf16(
                        af[mt], bzf[nt], accZ[mt][nt], 0, 0, 0);
                    accU[mt][nt] = __builtin_amdgcn_mfma_f32_16x16x32_bf16(
                        af[mt], buf[nt], accU[mt][nt], 0, 0, 0);
                }
            }
        }
        __syncthreads();   // all waves done with staging LDS
    }

    // ---- epilogue: sigmoid; a/bb -> LDS fp16 (C/D: col=ln15, row=quad*4+r)
    #pragma unroll
    for (int nt = 0; nt < 2; ++nt) {
        const int col = col0 + wc0 + nt * 16 + ln15;
        const int lc  = wc0 + nt * 16 + ln15;
        const float bzv = bz[col];
        const float bhv = bh[col];
        #pragma unroll
        for (int mt = 0; mt < 4; ++mt) {
            const int rb = wr0 + mt * 16 + quad * 4;
            #pragma unroll
            for (int r = 0; r < 4; ++r) {
                const float z = accZ[mt][nt][r] + bzv;
                const float g = 1.0f / (1.0f + __expf(-z));
                const float u = accU[mt][nt][r] + bhv;
                a_lds[(rb + r) * EPS + lc] = __float2half_rn(1.0f - g);
                b_lds[(rb + r) * EPS + lc] = __float2half_rn(g * u);
            }
        }
    }
    __syncthreads();

    // ---- sub-chunk (32-row) affine summaries: thread (s,h)
    const int s = tid >> 6;
    const int h = tid & 63;
    {
        float A = 1.0f, Bv = 0.0f;
        #pragma unroll 8
        for (int r = s * 32; r < s * 32 + 32; ++r) {
            const float a  = __half2float(a_lds[r * EPS + h]);
            const float bb = __half2float(b_lds[r * EPS + h]);
            Bv = fmaf(a, Bv, bb);
            A *= a;
        }
        float2 o; o.x = A; o.y = Bv;
        sub_lds[s * 64 + h] = o;
    }
    __syncthreads();

    // ---- publish block aggregate + batched lookback (one lane per h)
    if (tid < 64) {
        float A = 1.0f, Bv = 0.0f;
        #pragma unroll
        for (int s2 = 0; s2 < 4; ++s2) {
            const float2 g = sub_lds[s2 * 64 + tid];
            Bv = fmaf(g.x, Bv, g.y);
            A *= g.x;
        }
        union { float2 f; unsigned long long u; } pk;
        pk.f.x = A; pk.f.y = Bv;
        pk.u |= 1ull;                         // never 0 => unambiguous ready flag
        __hip_atomic_store(&agg[(size_t)(chain * kNT + t) * 64 + tid], pk.u,
                           __ATOMIC_RELAXED, __HIP_MEMORY_SCOPE_AGENT);

        // lookback over predecessors 0..t-1, 8 at a time (independent loads,
        // one L2/L3 latency per batch; fold strictly in order).
        float hs = h0[(size_t)b * kH + col0 + tid];
        for (int j0 = 0; j0 < t; j0 += 8) {
            const int nb = (t - j0 < 8) ? (t - j0) : 8;
            unsigned long long u[8];
            #pragma unroll
            for (int q2 = 0; q2 < 8; ++q2)
                if (q2 < nb)
                    u[q2] = __hip_atomic_load(
                        &agg[(size_t)(chain * kNT + j0 + q2) * 64 + tid],
                        __ATOMIC_RELAXED, __HIP_MEMORY_SCOPE_AGENT);
            #pragma unroll
            for (int q2 = 0; q2 < 8; ++q2) {
                if (q2 < nb) {
                    while (u[q2] == 0ull)
                        u[q2] = __hip_atomic_load(
                            &agg[(size_t)(chain * kNT + j0 + q2) * 64 + tid],
                            __ATOMIC_RELAXED, __HIP_MEMORY_SCOPE_AGENT);
                    union { unsigned long long u; float2 f; } qk; qk.u = u[q2];
                    hs = fmaf(qk.f.x, hs, qk.f.y);
                }
            }
        }
        hs_lds[tid] = hs;
    }
    __syncthreads();

    // ---- apply recurrence: thread (s,h) does its 32 rows, writes out
    {
        float hv = hs_lds[h];
        #pragma unroll
        for (int s2 = 0; s2 < s; ++s2) {
            const float2 g = sub_lds[s2 * 64 + h];
            hv = fmaf(g.x, hv, g.y);
        }
        #pragma unroll 8
        for (int r = 0; r < 32; ++r) {
            const int lr = s * 32 + r;
            const float a  = __half2float(a_lds[lr * EPS + h]);
            const float bb = __half2float(b_lds[lr * EPS + h]);
            hv = fmaf(a, hv, bb);
            __builtin_nontemporal_store(hv, &out[(size_t)(row0 + lr) * kH + col0 + h]);
        }
    }
}

extern "C" void kernel_launch(void* const* d_in, const int* in_sizes, int n_in,
                              void* d_out, int out_size, void* d_ws, size_t ws_size,
                              hipStream_t stream)
{
    const float* x  = (const float*)d_in[0];
    const float* h0 = (const float*)d_in[1];
    const float* Wz = (const float*)d_in[2];
    const float* bz = (const float*)d_in[3];
    const float* Wh = (const float*)d_in[4];
    const float* bh = (const float*)d_in[5];
    float* out = (float*)d_out;

    // Workspace: wzb/whb 131K each | agg 512K  => ~0.8 MB.
    unsigned char* ws = (unsigned char*)d_ws;
    unsigned short* wzb = (unsigned short*)ws;   ws += (size_t)kH * kD * 2;
    unsigned short* whb = (unsigned short*)ws;   ws += (size_t)kH * kD * 2;
    unsigned long long* agg = (unsigned long long*)ws;

    constexpr int PREP_ITEMS = 2 * (kH * kD / 4)
                             + kNChain * kNT * TH * 8 / 16;   // 65,536
    prep<<<PREP_ITEMS / 256, 256, 0, stream>>>(
        Wz, Wh, wzb, whb, (float4*)agg);
    gemm_scan_fused<<<kNChain * kNT, 256, 0, stream>>>(
        x, wzb, whb, bz, bh, h0, agg, out);
}